// Round 1
// 1176.845 us; speedup vs baseline: 1.2947x; 1.2947x over previous
//
#include <hip/hip_runtime.h>

#define B_ 8
#define S_ 1025
#define E_ 768
#define H_ 12
#define D_ 64
#define N_ 1024
#define M_OUT (B_*S_)   // 8200

typedef _Float16 half8 __attribute__((ext_vector_type(8)));
typedef float f32x4 __attribute__((ext_vector_type(4)));

#define MFMA16(A, B, C) __builtin_amdgcn_mfma_f32_16x16x32_f16((A), (B), (C), 0, 0, 0)

// ---------------- QKV projection: q/k/v = xt @ W^T + b, fp32 out -------------
// fp16x3-split MFMA GEMM. 128x128 tile, 4 waves, BK=32.
// A and W are both K-contiguous (W row-major is exactly B^T form for MFMA).
__global__ __launch_bounds__(256) void proj_qkv_kernel(
    const float* __restrict__ x,
    const float* __restrict__ Wq, const float* __restrict__ bq,
    const float* __restrict__ Wk, const float* __restrict__ bk,
    const float* __restrict__ Wv, const float* __restrict__ bv,
    float* __restrict__ qo, float* __restrict__ ko, float* __restrict__ vo)
{
  __shared__ _Float16 Ah[128][40];   // 40-half rows = 80B: 16B-aligned chunks, non-pow2 bank stride
  __shared__ _Float16 Al[128][40];
  __shared__ _Float16 Bh[128][40];
  __shared__ _Float16 Bl[128][40];

  const int which = blockIdx.z;
  const float* __restrict__ W    = (which == 0) ? Wq : (which == 1) ? Wk : Wv;
  const float* __restrict__ bias = (which == 0) ? bq : (which == 1) ? bk : bv;
  float* __restrict__ out        = (which == 0) ? qo : (which == 1) ? ko : vo;

  const int tid  = threadIdx.x;
  const int lane = tid & 63;
  const int wv   = tid >> 6;
  const int wm   = wv >> 1, wn = wv & 1;        // 2x2 wave grid, 64x64 per wave
  const int m0   = blockIdx.y * 128;
  const int n0   = blockIdx.x * 128;

  const int srow = tid >> 1;                    // staged row 0..127
  const int scol = (tid & 1) << 4;              // 0 or 16 (16 floats per thread)

  const int gm = m0 + srow;
  // xt row -> x row: b*S + 1 + i == gm + (gm>>10) + 1
  const float* __restrict__ aptr = x + (long)(gm + (gm >> 10) + 1) * E_ + scol;
  const float* __restrict__ bptr = W + (long)(n0 + srow) * E_ + scol;

  f32x4 acc[4][4] = {};

  const int fr = lane & 15;
  const int kb = (lane >> 4) << 3;              // k-octet per lane group
  const int ar0 = wm * 64 + fr;
  const int br0 = wn * 64 + fr;

  for (int k0 = 0; k0 < E_; k0 += 32) {
    float4 a0 = *(const float4*)(aptr + k0);
    float4 a1 = *(const float4*)(aptr + k0 + 4);
    float4 a2 = *(const float4*)(aptr + k0 + 8);
    float4 a3 = *(const float4*)(aptr + k0 + 12);
    float4 b0 = *(const float4*)(bptr + k0);
    float4 b1 = *(const float4*)(bptr + k0 + 4);
    float4 b2 = *(const float4*)(bptr + k0 + 8);
    float4 b3 = *(const float4*)(bptr + k0 + 12);
    __syncthreads();
    {
      float av[16] = {a0.x,a0.y,a0.z,a0.w,a1.x,a1.y,a1.z,a1.w,
                      a2.x,a2.y,a2.z,a2.w,a3.x,a3.y,a3.z,a3.w};
      float bvv[16] = {b0.x,b0.y,b0.z,b0.w,b1.x,b1.y,b1.z,b1.w,
                       b2.x,b2.y,b2.z,b2.w,b3.x,b3.y,b3.z,b3.w};
      half8 ah0, ah1, alo0, alo1, bh0, bh1, blo0, blo1;
      #pragma unroll
      for (int t = 0; t < 8; ++t) {
        _Float16 h;
        h = (_Float16)av[t];      ah0[t]  = h; alo0[t] = (_Float16)(av[t]   - (float)h);
        h = (_Float16)av[t+8];    ah1[t]  = h; alo1[t] = (_Float16)(av[t+8] - (float)h);
        h = (_Float16)bvv[t];     bh0[t]  = h; blo0[t] = (_Float16)(bvv[t]   - (float)h);
        h = (_Float16)bvv[t+8];   bh1[t]  = h; blo1[t] = (_Float16)(bvv[t+8] - (float)h);
      }
      *(half8*)&Ah[srow][scol]     = ah0;  *(half8*)&Ah[srow][scol + 8] = ah1;
      *(half8*)&Al[srow][scol]     = alo0; *(half8*)&Al[srow][scol + 8] = alo1;
      *(half8*)&Bh[srow][scol]     = bh0;  *(half8*)&Bh[srow][scol + 8] = bh1;
      *(half8*)&Bl[srow][scol]     = blo0; *(half8*)&Bl[srow][scol + 8] = blo1;
    }
    __syncthreads();

    half8 fah[4], fal[4], fbh[4], fbl[4];
    #pragma unroll
    for (int mi = 0; mi < 4; ++mi) {
      fah[mi] = *(const half8*)&Ah[ar0 + mi*16][kb];
      fal[mi] = *(const half8*)&Al[ar0 + mi*16][kb];
    }
    #pragma unroll
    for (int ni = 0; ni < 4; ++ni) {
      fbh[ni] = *(const half8*)&Bh[br0 + ni*16][kb];
      fbl[ni] = *(const half8*)&Bl[br0 + ni*16][kb];
    }
    #pragma unroll
    for (int mi = 0; mi < 4; ++mi)
      #pragma unroll
      for (int ni = 0; ni < 4; ++ni) {
        acc[mi][ni] = MFMA16(fah[mi], fbh[ni], acc[mi][ni]);
        acc[mi][ni] = MFMA16(fal[mi], fbh[ni], acc[mi][ni]);
        acc[mi][ni] = MFMA16(fah[mi], fbl[ni], acc[mi][ni]);
      }
  }

  // epilogue: C/D layout col=lane&15, row=(lane>>4)*4+reg  [verified mapping]
  const int rr = (lane >> 4) << 2;
  #pragma unroll
  for (int ni = 0; ni < 4; ++ni) {
    const int c = n0 + wn*64 + ni*16 + fr;
    const float bb = bias[c];
    #pragma unroll
    for (int mi = 0; mi < 4; ++mi) {
      const long row = m0 + wm*64 + mi*16 + rr;
      float* op = out + row * E_ + c;
      op[0]       = acc[mi][ni][0] + bb;
      op[E_]      = acc[mi][ni][1] + bb;
      op[2*E_]    = acc[mi][ni][2] + bb;
      op[3*(long)E_] = acc[mi][ni][3] + bb;
    }
  }
}

// ---------------- Output projection: out = vals @ Wo^T + bo, fp32 out --------
__global__ __launch_bounds__(256) void proj_out_kernel(
    const float* __restrict__ A, const float* __restrict__ W,
    const float* __restrict__ bias, float* __restrict__ out)
{
  __shared__ _Float16 Ah[128][40];
  __shared__ _Float16 Al[128][40];
  __shared__ _Float16 Bh[128][40];
  __shared__ _Float16 Bl[128][40];

  const int tid  = threadIdx.x;
  const int lane = tid & 63;
  const int wv   = tid >> 6;
  const int wm   = wv >> 1, wn = wv & 1;
  const int m0   = blockIdx.y * 128;
  const int n0   = blockIdx.x * 128;

  const int srow = tid >> 1;
  const int scol = (tid & 1) << 4;

  const int gm = m0 + srow;
  const bool aok = gm < M_OUT;
  const float* __restrict__ aptr = A + (long)gm * E_ + scol;
  const float* __restrict__ bptr = W + (long)(n0 + srow) * E_ + scol;

  f32x4 acc[4][4] = {};

  const int fr = lane & 15;
  const int kb = (lane >> 4) << 3;
  const int ar0 = wm * 64 + fr;
  const int br0 = wn * 64 + fr;

  for (int k0 = 0; k0 < E_; k0 += 32) {
    float4 a0 = make_float4(0.f,0.f,0.f,0.f), a1 = a0, a2 = a0, a3 = a0;
    if (aok) {
      a0 = *(const float4*)(aptr + k0);
      a1 = *(const float4*)(aptr + k0 + 4);
      a2 = *(const float4*)(aptr + k0 + 8);
      a3 = *(const float4*)(aptr + k0 + 12);
    }
    float4 b0 = *(const float4*)(bptr + k0);
    float4 b1 = *(const float4*)(bptr + k0 + 4);
    float4 b2 = *(const float4*)(bptr + k0 + 8);
    float4 b3 = *(const float4*)(bptr + k0 + 12);
    __syncthreads();
    {
      float av[16] = {a0.x,a0.y,a0.z,a0.w,a1.x,a1.y,a1.z,a1.w,
                      a2.x,a2.y,a2.z,a2.w,a3.x,a3.y,a3.z,a3.w};
      float bvv[16] = {b0.x,b0.y,b0.z,b0.w,b1.x,b1.y,b1.z,b1.w,
                       b2.x,b2.y,b2.z,b2.w,b3.x,b3.y,b3.z,b3.w};
      half8 ah0, ah1, alo0, alo1, bh0, bh1, blo0, blo1;
      #pragma unroll
      for (int t = 0; t < 8; ++t) {
        _Float16 h;
        h = (_Float16)av[t];      ah0[t]  = h; alo0[t] = (_Float16)(av[t]   - (float)h);
        h = (_Float16)av[t+8];    ah1[t]  = h; alo1[t] = (_Float16)(av[t+8] - (float)h);
        h = (_Float16)bvv[t];     bh0[t]  = h; blo0[t] = (_Float16)(bvv[t]   - (float)h);
        h = (_Float16)bvv[t+8];   bh1[t]  = h; blo1[t] = (_Float16)(bvv[t+8] - (float)h);
      }
      *(half8*)&Ah[srow][scol]     = ah0;  *(half8*)&Ah[srow][scol + 8] = ah1;
      *(half8*)&Al[srow][scol]     = alo0; *(half8*)&Al[srow][scol + 8] = alo1;
      *(half8*)&Bh[srow][scol]     = bh0;  *(half8*)&Bh[srow][scol + 8] = bh1;
      *(half8*)&Bl[srow][scol]     = blo0; *(half8*)&Bl[srow][scol + 8] = blo1;
    }
    __syncthreads();

    half8 fah[4], fal[4], fbh[4], fbl[4];
    #pragma unroll
    for (int mi = 0; mi < 4; ++mi) {
      fah[mi] = *(const half8*)&Ah[ar0 + mi*16][kb];
      fal[mi] = *(const half8*)&Al[ar0 + mi*16][kb];
    }
    #pragma unroll
    for (int ni = 0; ni < 4; ++ni) {
      fbh[ni] = *(const half8*)&Bh[br0 + ni*16][kb];
      fbl[ni] = *(const half8*)&Bl[br0 + ni*16][kb];
    }
    #pragma unroll
    for (int mi = 0; mi < 4; ++mi)
      #pragma unroll
      for (int ni = 0; ni < 4; ++ni) {
        acc[mi][ni] = MFMA16(fah[mi], fbh[ni], acc[mi][ni]);
        acc[mi][ni] = MFMA16(fal[mi], fbh[ni], acc[mi][ni]);
        acc[mi][ni] = MFMA16(fah[mi], fbl[ni], acc[mi][ni]);
      }
  }

  const int rr = (lane >> 4) << 2;
  #pragma unroll
  for (int ni = 0; ni < 4; ++ni) {
    const int c = n0 + wn*64 + ni*16 + fr;
    const float bb = bias[c];
    #pragma unroll
    for (int mi = 0; mi < 4; ++mi) {
      const int row = m0 + wm*64 + mi*16 + rr;
      #pragma unroll
      for (int j = 0; j < 4; ++j) {
        if (row + j < M_OUT)
          out[(long)(row + j) * E_ + c] = acc[mi][ni][j] + bb;
      }
    }
  }
}

// ---------------- c = cls @ Wc^T + bc ; cdenom = 1/sqrt(D*clip(|c|^2)) -------
__global__ __launch_bounds__(64) void cls_c_kernel(
    const float* __restrict__ x, const float* __restrict__ Wc, const float* __restrict__ bc,
    float* __restrict__ cbuf, float* __restrict__ cdenom)
{
  const int bh = blockIdx.x;
  const int b = bh / H_, h = bh % H_;
  const int d = threadIdx.x;
  const float* xr = x + (long)b*S_*E_;          // cls row (token 0)
  const float* wr = Wc + (long)(h*D_ + d)*E_;
  float acc = 0.f;
  for (int j = 0; j < E_; j += 4) {
    float4 xw = *(const float4*)&xr[j];
    float4 ww = *(const float4*)&wr[j];
    acc += xw.x*ww.x + xw.y*ww.y + xw.z*ww.z + xw.w*ww.w;
  }
  acc += bc[h*D_ + d];
  cbuf[bh*D_ + d] = acc;
  float sq = acc*acc;
  #pragma unroll
  for (int off = 32; off > 0; off >>= 1) sq += __shfl_xor(sq, off);
  if (d == 0) cdenom[bh] = rsqrtf((float)D_ * fmaxf(sq, 1e-5f));
}

// ---------------- main attention: 64x64 tile per block -----------------------
// writes UNNORMALIZED exp(s) to attn (fp32), row sums to rowl_g, PV/l to vals
__global__ __launch_bounds__(256) void attn_kernel(
    const float* __restrict__ qbuf, const float* __restrict__ kbuf, const float* __restrict__ vbuf,
    const float* __restrict__ cbuf, const float* __restrict__ cdenom,
    float* __restrict__ vals, float* __restrict__ rowl_g, float* __restrict__ attn)
{
  __shared__ float qst[64][68];   // [d][q]  (transposed)
  __shared__ float kvs[64][68];   // first [d][k] (K transposed), then [k][d] (V natural)
  __shared__ float pst[64][68];   // [k][q]  (P transposed)
  __shared__ float cs[64];
  __shared__ float rowscale[64];
  __shared__ float rowl[64];

  const int qt = blockIdx.x, h = blockIdx.y, b = blockIdx.z;
  const int bh = b * H_ + h;
  const int q0 = qt * 64;
  const int tid = threadIdx.x;
  const int tx = tid & 15, ty = tid >> 4;
  const int lr = tid >> 2;          // staged row 0..63
  const int lc = (tid & 3) * 16;    // staged col chunk

  {
    const float* src = &qbuf[((long)b*N_ + q0 + lr)*E_ + h*D_ + lc];
    float4 t0 = *(const float4*)(src);
    float4 t1 = *(const float4*)(src+4);
    float4 t2 = *(const float4*)(src+8);
    float4 t3 = *(const float4*)(src+12);
    float tmp[16] = {t0.x,t0.y,t0.z,t0.w,t1.x,t1.y,t1.z,t1.w,
                     t2.x,t2.y,t2.z,t2.w,t3.x,t3.y,t3.z,t3.w};
    #pragma unroll
    for (int t = 0; t < 16; ++t) qst[lc+t][lr] = tmp[t];
  }
  if (tid < 64) cs[tid] = cbuf[bh*D_ + tid];
  const float cdn = cdenom[bh];
  __syncthreads();

  if (tid < 64) {
    const int r = tid;
    float qn2 = 0.f, cq = 0.f;
    #pragma unroll 8
    for (int d = 0; d < 64; ++d) {
      float qv = qst[d][r];
      qn2 = fmaf(qv, qv, qn2);
      cq  = fmaf(cs[d], qv, cq);
    }
    rowscale[r] = cq * cdn / fmaxf(qn2, 1e-5f);
    rowl[r] = 0.f;
  }

  float acc[4][4] = {};

  for (int kt = 0; kt < 16; ++kt) {
    __syncthreads();   // prev PV done; rowscale/rowl init visible on first iter
    {  // stage K transposed: kvs[d][k]
      const float* src = &kbuf[((long)b*N_ + kt*64 + lr)*E_ + h*D_ + lc];
      float4 t0 = *(const float4*)(src);
      float4 t1 = *(const float4*)(src+4);
      float4 t2 = *(const float4*)(src+8);
      float4 t3 = *(const float4*)(src+12);
      float tmp[16] = {t0.x,t0.y,t0.z,t0.w,t1.x,t1.y,t1.z,t1.w,
                       t2.x,t2.y,t2.z,t2.w,t3.x,t3.y,t3.z,t3.w};
      #pragma unroll
      for (int t = 0; t < 16; ++t) kvs[lc+t][lr] = tmp[t];
    }
    __syncthreads();

    float sacc[4][4] = {};
    #pragma unroll 8
    for (int d = 0; d < 64; ++d) {
      float4 a4 = *(const float4*)&qst[d][ty*4];
      float4 b4 = *(const float4*)&kvs[d][tx*4];
      float av[4] = {a4.x,a4.y,a4.z,a4.w};
      float bv[4] = {b4.x,b4.y,b4.z,b4.w};
      #pragma unroll
      for (int i = 0; i < 4; ++i)
        #pragma unroll
        for (int j = 0; j < 4; ++j)
          sacc[i][j] = fmaf(av[i], bv[j], sacc[i][j]);
    }
    #pragma unroll
    for (int i = 0; i < 4; ++i) {
      const int r = ty*4 + i;
      const float sc = rowscale[r];
      float p0 = __expf(fminf(sacc[i][0]*sc, 60.f));
      float p1 = __expf(fminf(sacc[i][1]*sc, 60.f));
      float p2 = __expf(fminf(sacc[i][2]*sc, 60.f));
      float p3 = __expf(fminf(sacc[i][3]*sc, 60.f));
      pst[tx*4+0][r] = p0;
      pst[tx*4+1][r] = p1;
      pst[tx*4+2][r] = p2;
      pst[tx*4+3][r] = p3;
      float ps = p0+p1+p2+p3;
      ps += __shfl_xor(ps, 1);
      ps += __shfl_xor(ps, 2);
      ps += __shfl_xor(ps, 4);
      ps += __shfl_xor(ps, 8);
      if (tx == 0) rowl[r] += ps;
      *(float4*)&attn[((long)(bh*N_ + q0 + r) << 10) + kt*64 + tx*4] =
          make_float4(p0, p1, p2, p3);
    }
    __syncthreads();
    {  // stage V natural: kvs[k][d]
      const float* src = &vbuf[((long)b*N_ + kt*64 + lr)*E_ + h*D_ + lc];
      float4 t0 = *(const float4*)(src);
      float4 t1 = *(const float4*)(src+4);
      float4 t2 = *(const float4*)(src+8);
      float4 t3 = *(const float4*)(src+12);
      *(float4*)&kvs[lr][lc]    = t0;
      *(float4*)&kvs[lr][lc+4]  = t1;
      *(float4*)&kvs[lr][lc+8]  = t2;
      *(float4*)&kvs[lr][lc+12] = t3;
    }
    __syncthreads();

    #pragma unroll 8
    for (int c = 0; c < 64; ++c) {
      float4 a4 = *(const float4*)&pst[c][ty*4];
      float4 b4 = *(const float4*)&kvs[c][tx*4];
      float av[4] = {a4.x,a4.y,a4.z,a4.w};
      float bv[4] = {b4.x,b4.y,b4.z,b4.w};
      #pragma unroll
      for (int i = 0; i < 4; ++i)
        #pragma unroll
        for (int j = 0; j < 4; ++j)
          acc[i][j] = fmaf(av[i], bv[j], acc[i][j]);
    }
  }
  __syncthreads();

  #pragma unroll
  for (int i = 0; i < 4; ++i) {
    const int r = ty*4 + i;
    const float inv = 1.0f / rowl[r];
    float4 o = make_float4(acc[i][0]*inv, acc[i][1]*inv, acc[i][2]*inv, acc[i][3]*inv);
    *(float4*)&vals[((long)b*S_ + 1 + q0 + r)*E_ + h*D_ + tx*4] = o;
  }
  if (tid < 64) rowl_g[(long)bh*N_ + q0 + tid] = rowl[tid];
}

// ---------------- CLS output row (no softmax) --------------------------------
__global__ __launch_bounds__(256) void cls_attn_kernel(
    const float* __restrict__ x, const float* __restrict__ kbuf, const float* __restrict__ vbuf,
    const float* __restrict__ cbuf, const float* __restrict__ cdenom, float* __restrict__ vals)
{
  __shared__ float cs[64];
  __shared__ float part[4][64];
  const int bh = blockIdx.x;
  const int b = bh / H_, h = bh % H_;
  const int tid = threadIdx.x;
  const int wv = tid >> 6, lane = tid & 63;
  if (tid < 64) cs[tid] = cbuf[bh*D_ + tid];
  __syncthreads();
  float acc = 0.f;
  const long base0 = (long)b*N_*E_ + h*D_ + lane;
  for (int kk = wv*256; kk < wv*256 + 256; ++kk) {
    const long base = base0 + (long)kk*E_;
    float s = cs[lane] * kbuf[base];
    s += __shfl_xor(s, 1);  s += __shfl_xor(s, 2);  s += __shfl_xor(s, 4);
    s += __shfl_xor(s, 8);  s += __shfl_xor(s, 16); s += __shfl_xor(s, 32);
    acc = fmaf(s, vbuf[base], acc);
  }
  part[wv][lane] = acc;
  __syncthreads();
  if (tid < 64) {
    const float tot = (part[0][tid] + part[1][tid] + part[2][tid] + part[3][tid]) * cdenom[bh];
    const float cls = x[(long)b*S_*E_ + h*D_ + tid];
    vals[(long)b*S_*E_ + h*D_ + tid] = (cls + tot) * 0.5f;
  }
}

// ---------------- normalize stored attn in place (fp32) ----------------------
__global__ __launch_bounds__(256) void rescale_kernel(
    float* __restrict__ attn, const float* __restrict__ rowl_g)
{
  const long row = blockIdx.x;
  const float inv = 1.0f / rowl_g[row];
  float* p = attn + (row << 10) + threadIdx.x * 4;
  float4 u = *(float4*)p;
  u.x *= inv; u.y *= inv; u.z *= inv; u.w *= inv;
  *(float4*)p = u;
}

extern "C" void kernel_launch(void* const* d_in, const int* in_sizes, int n_in,
                              void* d_out, int out_size, void* d_ws, size_t ws_size,
                              hipStream_t stream) {
  (void)in_sizes; (void)n_in; (void)out_size; (void)ws_size;
  const float* x  = (const float*)d_in[0];
  const float* Wq = (const float*)d_in[1];
  const float* bq = (const float*)d_in[2];
  const float* Wk = (const float*)d_in[3];
  const float* bk = (const float*)d_in[4];
  const float* Wv = (const float*)d_in[5];
  const float* bv = (const float*)d_in[6];
  const float* Wc = (const float*)d_in[7];
  const float* bc = (const float*)d_in[8];
  const float* Wo = (const float*)d_in[9];
  const float* bo = (const float*)d_in[10];

  float* outp = (float*)d_out;
  float* attn = outp + (long)B_*S_*E_;   // fp32 outputs, concatenated flat

  // workspace (fp32): q,k,v (B*N*E each), vals (B*S*E), c, cdenom, rowl  ~101 MiB
  float* qb   = (float*)d_ws;
  float* kb   = qb + (long)B_*N_*E_;
  float* vb   = kb + (long)B_*N_*E_;
  float* vals = vb + (long)B_*N_*E_;
  float* cbuf = vals + (long)B_*S_*E_;
  float* cden = cbuf + B_*H_*D_;
  float* rowl = cden + B_*H_;

  proj_qkv_kernel<<<dim3(6, 64, 3), 256, 0, stream>>>(x, Wq, bq, Wk, bk, Wv, bv, qb, kb, vb);
  cls_c_kernel<<<B_*H_, 64, 0, stream>>>(x, Wc, bc, cbuf, cden);
  attn_kernel<<<dim3(16, H_, B_), 256, 0, stream>>>(qb, kb, vb, cbuf, cden, vals, rowl, attn);
  cls_attn_kernel<<<B_*H_, 256, 0, stream>>>(x, kb, vb, cbuf, cden, vals);
  rescale_kernel<<<B_*H_*N_, 256, 0, stream>>>(attn, rowl);
  proj_out_kernel<<<dim3(6, 65), 256, 0, stream>>>(vals, Wo, bo, outp);
}

// Round 2
// 1022.609 us; speedup vs baseline: 1.4900x; 1.1508x over previous
//
#include <hip/hip_runtime.h>

#define B_ 8
#define S_ 1025
#define E_ 768
#define H_ 12
#define D_ 64
#define N_ 1024
#define M_OUT (B_*S_)   // 8200

typedef _Float16 half8_t __attribute__((ext_vector_type(8)));
typedef short short8_t __attribute__((ext_vector_type(8)));
typedef float f32x4 __attribute__((ext_vector_type(4)));

#define MFMA_F16(A, B, C)  __builtin_amdgcn_mfma_f32_16x16x32_f16((A), (B), (C), 0, 0, 0)
#define MFMA_BF16(A, B, C) __builtin_amdgcn_mfma_f32_16x16x32_bf16((A), (B), (C), 0, 0, 0)

__device__ __forceinline__ unsigned short f2bf(float f) {
  unsigned u = __float_as_uint(f);
  u += 0x7FFFu + ((u >> 16) & 1u);          // RNE
  return (unsigned short)(u >> 16);
}
__device__ __forceinline__ float bf2f(unsigned short s) {
  return __uint_as_float(((unsigned)s) << 16);
}

// ---------------- QKV projection: q/k/v = xt @ W^T + b, fp32 out -------------
// fp16x3-split MFMA GEMM. 128x128 tile, 4 waves, BK=32.  (validated round 1)
__global__ __launch_bounds__(256) void proj_qkv_kernel(
    const float* __restrict__ x,
    const float* __restrict__ Wq, const float* __restrict__ bq,
    const float* __restrict__ Wk, const float* __restrict__ bk,
    const float* __restrict__ Wv, const float* __restrict__ bv,
    float* __restrict__ qo, float* __restrict__ ko, float* __restrict__ vo)
{
  __shared__ _Float16 Ah[128][40];
  __shared__ _Float16 Al[128][40];
  __shared__ _Float16 Bh[128][40];
  __shared__ _Float16 Bl[128][40];

  const int which = blockIdx.z;
  const float* __restrict__ W    = (which == 0) ? Wq : (which == 1) ? Wk : Wv;
  const float* __restrict__ bias = (which == 0) ? bq : (which == 1) ? bk : bv;
  float* __restrict__ out        = (which == 0) ? qo : (which == 1) ? ko : vo;

  const int tid  = threadIdx.x;
  const int lane = tid & 63;
  const int wv   = tid >> 6;
  const int wm   = wv >> 1, wn = wv & 1;
  const int m0   = blockIdx.y * 128;
  const int n0   = blockIdx.x * 128;

  const int srow = tid >> 1;
  const int scol = (tid & 1) << 4;

  const int gm = m0 + srow;
  const float* __restrict__ aptr = x + (long)(gm + (gm >> 10) + 1) * E_ + scol;
  const float* __restrict__ bptr = W + (long)(n0 + srow) * E_ + scol;

  f32x4 acc[4][4] = {};

  const int fr = lane & 15;
  const int kb = (lane >> 4) << 3;
  const int ar0 = wm * 64 + fr;
  const int br0 = wn * 64 + fr;

  for (int k0 = 0; k0 < E_; k0 += 32) {
    float4 a0 = *(const float4*)(aptr + k0);
    float4 a1 = *(const float4*)(aptr + k0 + 4);
    float4 a2 = *(const float4*)(aptr + k0 + 8);
    float4 a3 = *(const float4*)(aptr + k0 + 12);
    float4 b0 = *(const float4*)(bptr + k0);
    float4 b1 = *(const float4*)(bptr + k0 + 4);
    float4 b2 = *(const float4*)(bptr + k0 + 8);
    float4 b3 = *(const float4*)(bptr + k0 + 12);
    __syncthreads();
    {
      float av[16] = {a0.x,a0.y,a0.z,a0.w,a1.x,a1.y,a1.z,a1.w,
                      a2.x,a2.y,a2.z,a2.w,a3.x,a3.y,a3.z,a3.w};
      float bvv[16] = {b0.x,b0.y,b0.z,b0.w,b1.x,b1.y,b1.z,b1.w,
                       b2.x,b2.y,b2.z,b2.w,b3.x,b3.y,b3.z,b3.w};
      half8_t ah0, ah1, alo0, alo1, bh0, bh1, blo0, blo1;
      #pragma unroll
      for (int t = 0; t < 8; ++t) {
        _Float16 hh;
        hh = (_Float16)av[t];      ah0[t]  = hh; alo0[t] = (_Float16)(av[t]   - (float)hh);
        hh = (_Float16)av[t+8];    ah1[t]  = hh; alo1[t] = (_Float16)(av[t+8] - (float)hh);
        hh = (_Float16)bvv[t];     bh0[t]  = hh; blo0[t] = (_Float16)(bvv[t]   - (float)hh);
        hh = (_Float16)bvv[t+8];   bh1[t]  = hh; blo1[t] = (_Float16)(bvv[t+8] - (float)hh);
      }
      *(half8_t*)&Ah[srow][scol]     = ah0;  *(half8_t*)&Ah[srow][scol + 8] = ah1;
      *(half8_t*)&Al[srow][scol]     = alo0; *(half8_t*)&Al[srow][scol + 8] = alo1;
      *(half8_t*)&Bh[srow][scol]     = bh0;  *(half8_t*)&Bh[srow][scol + 8] = bh1;
      *(half8_t*)&Bl[srow][scol]     = blo0; *(half8_t*)&Bl[srow][scol + 8] = blo1;
    }
    __syncthreads();

    half8_t fah[4], fal[4], fbh[4], fbl[4];
    #pragma unroll
    for (int mi = 0; mi < 4; ++mi) {
      fah[mi] = *(const half8_t*)&Ah[ar0 + mi*16][kb];
      fal[mi] = *(const half8_t*)&Al[ar0 + mi*16][kb];
    }
    #pragma unroll
    for (int ni = 0; ni < 4; ++ni) {
      fbh[ni] = *(const half8_t*)&Bh[br0 + ni*16][kb];
      fbl[ni] = *(const half8_t*)&Bl[br0 + ni*16][kb];
    }
    #pragma unroll
    for (int mi = 0; mi < 4; ++mi)
      #pragma unroll
      for (int ni = 0; ni < 4; ++ni) {
        acc[mi][ni] = MFMA_F16(fah[mi], fbh[ni], acc[mi][ni]);
        acc[mi][ni] = MFMA_F16(fal[mi], fbh[ni], acc[mi][ni]);
        acc[mi][ni] = MFMA_F16(fah[mi], fbl[ni], acc[mi][ni]);
      }
  }

  const int rr = (lane >> 4) << 2;
  #pragma unroll
  for (int ni = 0; ni < 4; ++ni) {
    const int c = n0 + wn*64 + ni*16 + fr;
    const float bb = bias[c];
    #pragma unroll
    for (int mi = 0; mi < 4; ++mi) {
      const long row = m0 + wm*64 + mi*16 + rr;
      float* op = out + row * E_ + c;
      op[0]          = acc[mi][ni][0] + bb;
      op[E_]         = acc[mi][ni][1] + bb;
      op[2*E_]       = acc[mi][ni][2] + bb;
      op[3*(long)E_] = acc[mi][ni][3] + bb;
    }
  }
}

// ---------------- Output projection: out = vals @ Wo^T + bo, fp32 out --------
__global__ __launch_bounds__(256) void proj_out_kernel(
    const float* __restrict__ A, const float* __restrict__ W,
    const float* __restrict__ bias, float* __restrict__ out)
{
  __shared__ _Float16 Ah[128][40];
  __shared__ _Float16 Al[128][40];
  __shared__ _Float16 Bh[128][40];
  __shared__ _Float16 Bl[128][40];

  const int tid  = threadIdx.x;
  const int lane = tid & 63;
  const int wv   = tid >> 6;
  const int wm   = wv >> 1, wn = wv & 1;
  const int m0   = blockIdx.y * 128;
  const int n0   = blockIdx.x * 128;

  const int srow = tid >> 1;
  const int scol = (tid & 1) << 4;

  const int gm = m0 + srow;
  const bool aok = gm < M_OUT;
  const float* __restrict__ aptr = A + (long)gm * E_ + scol;
  const float* __restrict__ bptr = W + (long)(n0 + srow) * E_ + scol;

  f32x4 acc[4][4] = {};

  const int fr = lane & 15;
  const int kb = (lane >> 4) << 3;
  const int ar0 = wm * 64 + fr;
  const int br0 = wn * 64 + fr;

  for (int k0 = 0; k0 < E_; k0 += 32) {
    float4 a0 = make_float4(0.f,0.f,0.f,0.f), a1 = a0, a2 = a0, a3 = a0;
    if (aok) {
      a0 = *(const float4*)(aptr + k0);
      a1 = *(const float4*)(aptr + k0 + 4);
      a2 = *(const float4*)(aptr + k0 + 8);
      a3 = *(const float4*)(aptr + k0 + 12);
    }
    float4 b0 = *(const float4*)(bptr + k0);
    float4 b1 = *(const float4*)(bptr + k0 + 4);
    float4 b2 = *(const float4*)(bptr + k0 + 8);
    float4 b3 = *(const float4*)(bptr + k0 + 12);
    __syncthreads();
    {
      float av[16] = {a0.x,a0.y,a0.z,a0.w,a1.x,a1.y,a1.z,a1.w,
                      a2.x,a2.y,a2.z,a2.w,a3.x,a3.y,a3.z,a3.w};
      float bvv[16] = {b0.x,b0.y,b0.z,b0.w,b1.x,b1.y,b1.z,b1.w,
                       b2.x,b2.y,b2.z,b2.w,b3.x,b3.y,b3.z,b3.w};
      half8_t ah0, ah1, alo0, alo1, bh0, bh1, blo0, blo1;
      #pragma unroll
      for (int t = 0; t < 8; ++t) {
        _Float16 hh;
        hh = (_Float16)av[t];      ah0[t]  = hh; alo0[t] = (_Float16)(av[t]   - (float)hh);
        hh = (_Float16)av[t+8];    ah1[t]  = hh; alo1[t] = (_Float16)(av[t+8] - (float)hh);
        hh = (_Float16)bvv[t];     bh0[t]  = hh; blo0[t] = (_Float16)(bvv[t]   - (float)hh);
        hh = (_Float16)bvv[t+8];   bh1[t]  = hh; blo1[t] = (_Float16)(bvv[t+8] - (float)hh);
      }
      *(half8_t*)&Ah[srow][scol]     = ah0;  *(half8_t*)&Ah[srow][scol + 8] = ah1;
      *(half8_t*)&Al[srow][scol]     = alo0; *(half8_t*)&Al[srow][scol + 8] = alo1;
      *(half8_t*)&Bh[srow][scol]     = bh0;  *(half8_t*)&Bh[srow][scol + 8] = bh1;
      *(half8_t*)&Bl[srow][scol]     = blo0; *(half8_t*)&Bl[srow][scol + 8] = blo1;
    }
    __syncthreads();

    half8_t fah[4], fal[4], fbh[4], fbl[4];
    #pragma unroll
    for (int mi = 0; mi < 4; ++mi) {
      fah[mi] = *(const half8_t*)&Ah[ar0 + mi*16][kb];
      fal[mi] = *(const half8_t*)&Al[ar0 + mi*16][kb];
    }
    #pragma unroll
    for (int ni = 0; ni < 4; ++ni) {
      fbh[ni] = *(const half8_t*)&Bh[br0 + ni*16][kb];
      fbl[ni] = *(const half8_t*)&Bl[br0 + ni*16][kb];
    }
    #pragma unroll
    for (int mi = 0; mi < 4; ++mi)
      #pragma unroll
      for (int ni = 0; ni < 4; ++ni) {
        acc[mi][ni] = MFMA_F16(fah[mi], fbh[ni], acc[mi][ni]);
        acc[mi][ni] = MFMA_F16(fal[mi], fbh[ni], acc[mi][ni]);
        acc[mi][ni] = MFMA_F16(fah[mi], fbl[ni], acc[mi][ni]);
      }
  }

  const int rr = (lane >> 4) << 2;
  #pragma unroll
  for (int ni = 0; ni < 4; ++ni) {
    const int c = n0 + wn*64 + ni*16 + fr;
    const float bb = bias[c];
    #pragma unroll
    for (int mi = 0; mi < 4; ++mi) {
      const int row = m0 + wm*64 + mi*16 + rr;
      #pragma unroll
      for (int j = 0; j < 4; ++j) {
        if (row + j < M_OUT)
          out[(long)(row + j) * E_ + c] = acc[mi][ni][j] + bb;
      }
    }
  }
}

// ---------------- c = cls @ Wc^T + bc ; cdenom = 1/sqrt(D*clip(|c|^2)) -------
__global__ __launch_bounds__(64) void cls_c_kernel(
    const float* __restrict__ x, const float* __restrict__ Wc, const float* __restrict__ bc,
    float* __restrict__ cbuf, float* __restrict__ cdenom)
{
  const int bh = blockIdx.x;
  const int b = bh / H_, h = bh % H_;
  const int d = threadIdx.x;
  const float* xr = x + (long)b*S_*E_;
  const float* wr = Wc + (long)(h*D_ + d)*E_;
  float acc = 0.f;
  for (int j = 0; j < E_; j += 4) {
    float4 xw = *(const float4*)&xr[j];
    float4 ww = *(const float4*)&wr[j];
    acc += xw.x*ww.x + xw.y*ww.y + xw.z*ww.z + xw.w*ww.w;
  }
  acc += bc[h*D_ + d];
  cbuf[bh*D_ + d] = acc;
  float sq = acc*acc;
  #pragma unroll
  for (int off = 32; off > 0; off >>= 1) sq += __shfl_xor(sq, off);
  if (d == 0) cdenom[bh] = rsqrtf((float)D_ * fmaxf(sq, 1e-5f));
}

// ---------------- main attention: 64x64 tile per block, MFMA -----------------
// QK^T in fp16x3 (range-safe for q/k), PV in bf16x3 (range-safe for P<=e^60).
// Writes UNNORMALIZED exp(s) to attn (fp32), row sums to rowl_g, PV/l to vals.
__global__ __launch_bounds__(256) void attn_kernel(
    const float* __restrict__ qbuf, const float* __restrict__ kbuf, const float* __restrict__ vbuf,
    const float* __restrict__ cbuf, const float* __restrict__ cdenom,
    float* __restrict__ vals, float* __restrict__ rowl_g, float* __restrict__ attn)
{
  // rows padded to 72 elems (144B): 16B-aligned, non-pathological bank stride
  __shared__ short QPh[64][72];   // Q f16 hi, later P bf16 hi (Q frags preloaded to regs)
  __shared__ short QPl[64][72];   // Q f16 lo, later P bf16 lo
  __shared__ short Kh[64][72];    // K f16 hi, natural [n][d]
  __shared__ short Kl[64][72];
  __shared__ short Vth[64][72];   // V bf16 hi, transposed [d][k]
  __shared__ short Vtl[64][72];
  __shared__ float cs[64];
  __shared__ float rowscale_s[64];
  __shared__ float rowsum2[2][64];

  const int qt = blockIdx.x, h = blockIdx.y, b = blockIdx.z;
  const int bh = b * H_ + h;
  const int q0 = qt * 64;
  const int tid  = threadIdx.x;
  const int lane = tid & 63;
  const int wv   = tid >> 6;
  const int wm   = wv >> 1, wn = wv & 1;   // 2x2 wave grid, 32x32 per wave
  const int fr   = lane & 15;
  const int g    = lane >> 4;
  const int lr   = tid >> 2;               // staging row 0..63
  const int lc   = (tid & 3) * 16;         // staging col chunk

  // ---- stage Q (f16 split, natural [q][d]) ----
  {
    const float* src = &qbuf[((long)b*N_ + q0 + lr)*E_ + h*D_ + lc];
    float4 t0 = *(const float4*)(src);
    float4 t1 = *(const float4*)(src+4);
    float4 t2 = *(const float4*)(src+8);
    float4 t3 = *(const float4*)(src+12);
    float tmp[16] = {t0.x,t0.y,t0.z,t0.w,t1.x,t1.y,t1.z,t1.w,
                     t2.x,t2.y,t2.z,t2.w,t3.x,t3.y,t3.z,t3.w};
    half8_t h0, h1, l0, l1;
    #pragma unroll
    for (int t = 0; t < 8; ++t) {
      _Float16 hh;
      hh = (_Float16)tmp[t];   h0[t] = hh; l0[t] = (_Float16)(tmp[t]   - (float)hh);
      hh = (_Float16)tmp[t+8]; h1[t] = hh; l1[t] = (_Float16)(tmp[t+8] - (float)hh);
    }
    *(half8_t*)&QPh[lr][lc]   = h0; *(half8_t*)&QPh[lr][lc+8] = h1;
    *(half8_t*)&QPl[lr][lc]   = l0; *(half8_t*)&QPl[lr][lc+8] = l1;
  }
  if (tid < 64) cs[tid] = cbuf[bh*D_ + tid];
  const float cdn = cdenom[bh];
  __syncthreads();

  // ---- rowscale (serial-64; small) ----
  if (tid < 64) {
    const _Float16* qh = (const _Float16*)QPh[tid];
    const _Float16* ql = (const _Float16*)QPl[tid];
    float qn2 = 0.f, cq = 0.f;
    #pragma unroll 8
    for (int d = 0; d < 64; ++d) {
      float qv = (float)qh[d] + (float)ql[d];
      qn2 = fmaf(qv, qv, qn2);
      cq  = fmaf(cs[d], qv, cq);
    }
    rowscale_s[tid] = cq * cdn / fmaxf(qn2, 1e-5f);
  }

  // ---- preload Q fragments (frees QP buffers for P) ----
  half8_t qfh[2][2], qfl[2][2];
  #pragma unroll
  for (int mi = 0; mi < 2; ++mi)
    #pragma unroll
    for (int ks = 0; ks < 2; ++ks) {
      qfh[mi][ks] = *(const half8_t*)&QPh[wm*32 + mi*16 + fr][ks*32 + g*8];
      qfl[mi][ks] = *(const half8_t*)&QPl[wm*32 + mi*16 + fr][ks*32 + g*8];
    }
  __syncthreads();

  // per-thread row scales for its 8 rows (2 mi x 4 j)
  float rs[2][4];
  #pragma unroll
  for (int mi = 0; mi < 2; ++mi)
    #pragma unroll
    for (int j = 0; j < 4; ++j)
      rs[mi][j] = rowscale_s[wm*32 + mi*16 + g*4 + j];

  float psum[2][4] = {};
  f32x4 acc[2][2] = {};

  for (int kt = 0; kt < 16; ++kt) {
    __syncthreads();   // prev tile fully consumed
    {  // stage K natural [n][d], f16 split
      const float* src = &kbuf[((long)b*N_ + kt*64 + lr)*E_ + h*D_ + lc];
      float4 t0 = *(const float4*)(src);
      float4 t1 = *(const float4*)(src+4);
      float4 t2 = *(const float4*)(src+8);
      float4 t3 = *(const float4*)(src+12);
      float tmp[16] = {t0.x,t0.y,t0.z,t0.w,t1.x,t1.y,t1.z,t1.w,
                       t2.x,t2.y,t2.z,t2.w,t3.x,t3.y,t3.z,t3.w};
      half8_t h0, h1, l0, l1;
      #pragma unroll
      for (int t = 0; t < 8; ++t) {
        _Float16 hh;
        hh = (_Float16)tmp[t];   h0[t] = hh; l0[t] = (_Float16)(tmp[t]   - (float)hh);
        hh = (_Float16)tmp[t+8]; h1[t] = hh; l1[t] = (_Float16)(tmp[t+8] - (float)hh);
      }
      *(half8_t*)&Kh[lr][lc]   = h0; *(half8_t*)&Kh[lr][lc+8] = h1;
      *(half8_t*)&Kl[lr][lc]   = l0; *(half8_t*)&Kl[lr][lc+8] = l1;
    }
    {  // stage V transposed [d][k], bf16 split (scatter)
      const float* src = &vbuf[((long)b*N_ + kt*64 + lr)*E_ + h*D_ + lc];
      float4 t0 = *(const float4*)(src);
      float4 t1 = *(const float4*)(src+4);
      float4 t2 = *(const float4*)(src+8);
      float4 t3 = *(const float4*)(src+12);
      float tmp[16] = {t0.x,t0.y,t0.z,t0.w,t1.x,t1.y,t1.z,t1.w,
                       t2.x,t2.y,t2.z,t2.w,t3.x,t3.y,t3.z,t3.w};
      #pragma unroll
      for (int t = 0; t < 16; ++t) {
        float f = tmp[t];
        unsigned short hb = f2bf(f);
        Vth[lc+t][lr] = (short)hb;
        Vtl[lc+t][lr] = (short)f2bf(f - bf2f(hb));
      }
    }
    __syncthreads();

    // ---- QK^T (fp16x3) ----
    f32x4 sacc[2][2] = {};
    #pragma unroll
    for (int ks = 0; ks < 2; ++ks) {
      half8_t kfh[2], kfl[2];
      #pragma unroll
      for (int ni = 0; ni < 2; ++ni) {
        kfh[ni] = *(const half8_t*)&Kh[wn*32 + ni*16 + fr][ks*32 + g*8];
        kfl[ni] = *(const half8_t*)&Kl[wn*32 + ni*16 + fr][ks*32 + g*8];
      }
      #pragma unroll
      for (int mi = 0; mi < 2; ++mi)
        #pragma unroll
        for (int ni = 0; ni < 2; ++ni) {
          sacc[mi][ni] = MFMA_F16(qfh[mi][ks], kfh[ni], sacc[mi][ni]);
          sacc[mi][ni] = MFMA_F16(qfl[mi][ks], kfh[ni], sacc[mi][ni]);
          sacc[mi][ni] = MFMA_F16(qfh[mi][ks], kfl[ni], sacc[mi][ni]);
        }
    }

    // ---- softmax-exp + global store + bf16 split into P buffers ----
    #pragma unroll
    for (int mi = 0; mi < 2; ++mi)
      #pragma unroll
      for (int ni = 0; ni < 2; ++ni)
        #pragma unroll
        for (int j = 0; j < 4; ++j) {
          const int row = wm*32 + mi*16 + g*4 + j;
          const int col = wn*32 + ni*16 + fr;
          float s = sacc[mi][ni][j] * rs[mi][j];
          float p = __expf(fminf(s, 60.f));
          psum[mi][j] += p;
          attn[((long)(bh*N_ + q0 + row) << 10) + kt*64 + col] = p;
          unsigned short hb = f2bf(p);
          QPh[row][col] = (short)hb;
          QPl[row][col] = (short)f2bf(p - bf2f(hb));
        }
    __syncthreads();   // P visible to all waves

    // ---- PV (bf16x3) ----
    #pragma unroll
    for (int ks = 0; ks < 2; ++ks) {
      short8_t pfh[2], pfl[2], vfh[2], vfl[2];
      #pragma unroll
      for (int mi = 0; mi < 2; ++mi) {
        pfh[mi] = *(const short8_t*)&QPh[wm*32 + mi*16 + fr][ks*32 + g*8];
        pfl[mi] = *(const short8_t*)&QPl[wm*32 + mi*16 + fr][ks*32 + g*8];
      }
      #pragma unroll
      for (int nj = 0; nj < 2; ++nj) {
        vfh[nj] = *(const short8_t*)&Vth[wn*32 + nj*16 + fr][ks*32 + g*8];
        vfl[nj] = *(const short8_t*)&Vtl[wn*32 + nj*16 + fr][ks*32 + g*8];
      }
      #pragma unroll
      for (int mi = 0; mi < 2; ++mi)
        #pragma unroll
        for (int nj = 0; nj < 2; ++nj) {
          acc[mi][nj] = MFMA_BF16(pfh[mi], vfh[nj], acc[mi][nj]);
          acc[mi][nj] = MFMA_BF16(pfl[mi], vfh[nj], acc[mi][nj]);
          acc[mi][nj] = MFMA_BF16(pfh[mi], vfl[nj], acc[mi][nj]);
        }
    }
  }

  // ---- row sums: reduce over the 16 cols each lane-group covers ----
  #pragma unroll
  for (int mi = 0; mi < 2; ++mi)
    #pragma unroll
    for (int j = 0; j < 4; ++j) {
      float v = psum[mi][j];
      v += __shfl_xor(v, 1);
      v += __shfl_xor(v, 2);
      v += __shfl_xor(v, 4);
      v += __shfl_xor(v, 8);
      psum[mi][j] = v;
    }
  __syncthreads();
  if (fr == 0) {
    #pragma unroll
    for (int mi = 0; mi < 2; ++mi)
      #pragma unroll
      for (int j = 0; j < 4; ++j)
        rowsum2[wn][wm*32 + mi*16 + g*4 + j] = psum[mi][j];
  }
  __syncthreads();

  if (tid < 64)
    rowl_g[(long)bh*N_ + q0 + tid] = rowsum2[0][tid] + rowsum2[1][tid];

  // ---- epilogue: O = acc / rowl ----
  #pragma unroll
  for (int mi = 0; mi < 2; ++mi)
    #pragma unroll
    for (int j = 0; j < 4; ++j) {
      const int row = wm*32 + mi*16 + g*4 + j;
      const float inv = 1.0f / (rowsum2[0][row] + rowsum2[1][row]);
      #pragma unroll
      for (int nj = 0; nj < 2; ++nj) {
        const int col = wn*32 + nj*16 + fr;
        vals[((long)b*S_ + 1 + q0 + row)*E_ + h*D_ + col] = acc[mi][nj][j] * inv;
      }
    }
}

// ---------------- CLS output row (no softmax) --------------------------------
__global__ __launch_bounds__(256) void cls_attn_kernel(
    const float* __restrict__ x, const float* __restrict__ kbuf, const float* __restrict__ vbuf,
    const float* __restrict__ cbuf, const float* __restrict__ cdenom, float* __restrict__ vals)
{
  __shared__ float cs[64];
  __shared__ float part[4][64];
  const int bh = blockIdx.x;
  const int b = bh / H_, h = bh % H_;
  const int tid = threadIdx.x;
  const int wv = tid >> 6, lane = tid & 63;
  if (tid < 64) cs[tid] = cbuf[bh*D_ + tid];
  __syncthreads();
  float acc = 0.f;
  const long base0 = (long)b*N_*E_ + h*D_ + lane;
  for (int kk = wv*256; kk < wv*256 + 256; ++kk) {
    const long base = base0 + (long)kk*E_;
    float s = cs[lane] * kbuf[base];
    s += __shfl_xor(s, 1);  s += __shfl_xor(s, 2);  s += __shfl_xor(s, 4);
    s += __shfl_xor(s, 8);  s += __shfl_xor(s, 16); s += __shfl_xor(s, 32);
    acc = fmaf(s, vbuf[base], acc);
  }
  part[wv][lane] = acc;
  __syncthreads();
  if (tid < 64) {
    const float tot = (part[0][tid] + part[1][tid] + part[2][tid] + part[3][tid]) * cdenom[bh];
    const float cls = x[(long)b*S_*E_ + h*D_ + tid];
    vals[(long)b*S_*E_ + h*D_ + tid] = (cls + tot) * 0.5f;
  }
}

// ---------------- normalize stored attn in place (fp32) ----------------------
__global__ __launch_bounds__(256) void rescale_kernel(
    float* __restrict__ attn, const float* __restrict__ rowl_g)
{
  const long row = blockIdx.x;
  const float inv = 1.0f / rowl_g[row];
  float* p = attn + (row << 10) + threadIdx.x * 4;
  float4 u = *(float4*)p;
  u.x *= inv; u.y *= inv; u.z *= inv; u.w *= inv;
  *(float4*)p = u;
}

extern "C" void kernel_launch(void* const* d_in, const int* in_sizes, int n_in,
                              void* d_out, int out_size, void* d_ws, size_t ws_size,
                              hipStream_t stream) {
  (void)in_sizes; (void)n_in; (void)out_size; (void)ws_size;
  const float* x  = (const float*)d_in[0];
  const float* Wq = (const float*)d_in[1];
  const float* bq = (const float*)d_in[2];
  const float* Wk = (const float*)d_in[3];
  const float* bk = (const float*)d_in[4];
  const float* Wv = (const float*)d_in[5];
  const float* bv = (const float*)d_in[6];
  const float* Wc = (const float*)d_in[7];
  const float* bc = (const float*)d_in[8];
  const float* Wo = (const float*)d_in[9];
  const float* bo = (const float*)d_in[10];

  float* outp = (float*)d_out;
  float* attn = outp + (long)B_*S_*E_;

  float* qb   = (float*)d_ws;
  float* kb   = qb + (long)B_*N_*E_;
  float* vb   = kb + (long)B_*N_*E_;
  float* vals = vb + (long)B_*N_*E_;
  float* cbuf = vals + (long)B_*S_*E_;
  float* cden = cbuf + B_*H_*D_;
  float* rowl = cden + B_*H_;

  proj_qkv_kernel<<<dim3(6, 64, 3), 256, 0, stream>>>(x, Wq, bq, Wk, bk, Wv, bv, qb, kb, vb);
  cls_c_kernel<<<B_*H_, 64, 0, stream>>>(x, Wc, bc, cbuf, cden);
  attn_kernel<<<dim3(16, H_, B_), 256, 0, stream>>>(qb, kb, vb, cbuf, cden, vals, rowl, attn);
  cls_attn_kernel<<<B_*H_, 256, 0, stream>>>(x, kb, vb, cbuf, cden, vals);
  rescale_kernel<<<B_*H_*N_, 256, 0, stream>>>(attn, rowl);
  proj_out_kernel<<<dim3(6, 65), 256, 0, stream>>>(vals, Wo, bo, outp);
}